// Round 23
// baseline (217.824 us; speedup 1.0000x reference)
//
#include <hip/hip_runtime.h>
#include <hip/hip_fp16.h>
#include <math.h>
#include <float.h>

#define NV 50000
#define NR 500
#define EVV 400000
#define EVI 100000
#define EIV 100000

#define CB_VV 0
#define CB_VI 50000
#define CB_IV 50500
#define CNT_LEN 100500
#define NREP 8
#define RB_VV 0
#define RB_VI 50004
#define RB_IV 50508
#define RP_LEN 100512
#define TILE 1024
#define T_VV 49
#define T_IV 49
#define T_TOT 99
#define HB1 2344
#define FB4 586
#define PB 12500
#define GBV 2048
#define NBQ 1563
#define RSB 16

// ---------------- hist: 1 edge/thread, XCD-local replicated counters ----------------
__global__ void hist_all_kernel(const int* __restrict__ vv_s, const int* __restrict__ vv_d,
                                const int* __restrict__ vi_d, const int* __restrict__ iv_d,
                                unsigned* __restrict__ cnt_rep, unsigned* __restrict__ rank_all) {
  int e = blockIdx.x * 256 + threadIdx.x;
  unsigned rbase = (unsigned)(blockIdx.x & (NREP - 1)) * CNT_LEN;
  if (e < EVV) {
    int s = vv_s[e], d = vv_d[e];
    if (s != d) rank_all[e] = atomicAdd(&cnt_rep[rbase + CB_VV + d], 1u);
  } else if (e < EVV + EVI) {
    rank_all[e] = atomicAdd(&cnt_rep[rbase + CB_VI + vi_d[e - EVV]], 1u);
  } else if (e < EVV + EVI + EIV) {
    rank_all[e] = atomicAdd(&cnt_rep[rbase + CB_IV + iv_d[e - EVV - EVI]], 1u);
  }
}

__device__ __forceinline__ void tile_decode(int b, int& cb, int& rb, int& n, int& base,
                                            int& topo, int& lt) {
  topo = (b < T_VV) ? 0 : (b == T_VV) ? 1 : 2;
  lt   = (topo == 0) ? b : (topo == 1) ? 0 : b - T_VV - 1;
  cb   = (topo == 0) ? CB_VV : (topo == 1) ? CB_VI : CB_IV;
  rb   = (topo == 0) ? RB_VV : (topo == 1) ? RB_VI : RB_IV;
  n    = (topo == 1) ? NR : NV;
  base = lt * TILE;
}

__global__ void tilesum_kernel(const unsigned* __restrict__ cnt_rep, unsigned* __restrict__ tsum) {
  int cb, rb, n, base, topo, lt;
  tile_decode(blockIdx.x, cb, rb, n, base, topo, lt);
  int t = threadIdx.x, lane = t & 63, wid = t >> 6;
  unsigned s = 0;
  #pragma unroll
  for (int j = 0; j < 4; ++j) {
    int i = base + t + j * 256;
    if (i < n) {
      #pragma unroll
      for (int r = 0; r < NREP; ++r) s += cnt_rep[r * CNT_LEN + cb + i];
    }
  }
  #pragma unroll
  for (int off = 32; off > 0; off >>= 1) s += (unsigned)__shfl_xor((int)s, off, 64);
  __shared__ unsigned wt[4];
  if (lane == 0) wt[wid] = s;
  __syncthreads();
  if (t == 0) tsum[blockIdx.x] = wt[0] + wt[1] + wt[2] + wt[3];
}

__global__ void scanwrite_kernel(const unsigned* __restrict__ cnt_rep,
                                 const unsigned* __restrict__ tsum,
                                 unsigned* __restrict__ rp_all,
                                 unsigned* __restrict__ roff) {
  int cb, rb, n, base, topo, lt;
  tile_decode(blockIdx.x, cb, rb, n, base, topo, lt);
  int t = threadIdx.x, lane = t & 63, wid = t >> 6;
  __shared__ unsigned sprefix;
  __shared__ unsigned wt[4];
  if (wid == 0) {
    int first = (topo == 0) ? 0 : (topo == 1) ? T_VV : T_VV + 1;
    int cntT  = (topo == 1) ? 1 : T_VV;
    unsigned tv = (lane < cntT) ? tsum[first + lane] : 0u;
    unsigned vp = (lane < lt) ? tv : 0u;
    unsigned vt = tv;
    #pragma unroll
    for (int off = 32; off > 0; off >>= 1) {
      vp += (unsigned)__shfl_xor((int)vp, off, 64);
      vt += (unsigned)__shfl_xor((int)vt, off, 64);
    }
    if (lane == 0) {
      sprefix = vp;
      if (lt == 0) rp_all[rb + n] = vt;
    }
  }
  int i0 = base + t * 4;
  unsigned c[4] = {0u, 0u, 0u, 0u};
  #pragma unroll
  for (int j = 0; j < 4; ++j) {
    int i = i0 + j;
    if (i < n) {
      unsigned acc = 0;
      #pragma unroll
      for (int r = 0; r < NREP; ++r) {
        roff[r * CNT_LEN + cb + i] = acc;
        acc += cnt_rep[r * CNT_LEN + cb + i];
      }
      c[j] = acc;
    }
  }
  unsigned s4 = c[0] + c[1] + c[2] + c[3];
  unsigned inc = s4;
  #pragma unroll
  for (int off = 1; off < 64; off <<= 1) {
    unsigned v = (unsigned)__shfl_up((int)inc, off, 64);
    if (lane >= off) inc += v;
  }
  if (lane == 63) wt[wid] = inc;
  __syncthreads();
  unsigned wb = sprefix;
  #pragma unroll
  for (int w = 0; w < 4; ++w) if (w < wid) wb += wt[w];
  unsigned p0 = wb + inc - s4;
  unsigned p1 = p0 + c[0], p2 = p1 + c[1], p3 = p2 + c[2];
  if (i0 + 3 < n) {
    *(uint4*)&rp_all[rb + i0] = make_uint4(p0, p1, p2, p3);
  } else if (i0 < n) {
    rp_all[rb + i0] = p0;
    if (i0 + 1 < n) rp_all[rb + i0 + 1] = p1;
    if (i0 + 2 < n) rp_all[rb + i0 + 2] = p2;
  }
}

// ---------------- fill (rank+roff based, atomic-free, 4 edges/thread) + 4x d=6 proj ------
__global__ void fill_proj_kernel(const int* __restrict__ vv_s, const int* __restrict__ vv_d,
                                 const int* __restrict__ vi_s, const int* __restrict__ vi_d,
                                 const int* __restrict__ iv_s, const int* __restrict__ iv_d,
                                 const unsigned* __restrict__ rp_all,
                                 const unsigned* __restrict__ roff,
                                 const unsigned* __restrict__ rank_all,
                                 int* __restrict__ src_all,
                                 const float* __restrict__ x,
                                 const float* __restrict__ W0, const float* __restrict__ b0,
                                 const float* __restrict__ W1, const float* __restrict__ b1,
                                 const float* __restrict__ W2, const float* __restrict__ b2,
                                 const float* __restrict__ W3, const float* __restrict__ b3,
                                 __half* __restrict__ out0, __half* __restrict__ out1,
                                 __half* __restrict__ out2, __half* __restrict__ out3) {
  if (blockIdx.x < FB4) {
    int t0 = blockIdx.x * 1024 + threadIdx.x;
    #pragma unroll
    for (int j = 0; j < 4; ++j) {
      int e = t0 + j * 256;
      unsigned rb2 = (unsigned)((e >> 8) & (NREP - 1)) * CNT_LEN;
      if (e < EVV) {
        int s = vv_s[e], d = vv_d[e];
        if (s != d) {
          unsigned pos = rp_all[RB_VV + d] + roff[rb2 + CB_VV + d] + rank_all[e];
          __builtin_nontemporal_store(s, &src_all[pos]);
        }
      } else if (e < EVV + EVI) {
        int i = e - EVV;
        int d = vi_d[i];
        unsigned pos = rp_all[RB_VI + d] + roff[rb2 + CB_VI + d] + rank_all[e];
        __builtin_nontemporal_store(vi_s[i], &src_all[EVV + pos]);
      } else if (e < EVV + EVI + EIV) {
        int i = e - EVV - EVI;
        int d = iv_d[i];
        unsigned pos = rp_all[RB_IV + d] + roff[rb2 + CB_IV + d] + rank_all[e];
        __builtin_nontemporal_store(iv_s[i], &src_all[EVV + EVI + pos]);
      }
    }
  } else {
    int t = (blockIdx.x - FB4) * 256 + threadIdx.x;
    if (t >= NV * 64) return;
    int row = t >> 6, c = t & 63;
    const float* xr = x + (size_t)row * 6;
    float x0 = xr[0], x1 = xr[1], x2 = xr[2], x3 = xr[3], x4 = xr[4], x5 = xr[5];
    float a0 = b0[c], a1 = b1[c], a2 = b2[c], a3 = b3[c];
    a0 = fmaf(x0, W0[0 * 64 + c], a0); a1 = fmaf(x0, W1[0 * 64 + c], a1);
    a2 = fmaf(x0, W2[0 * 64 + c], a2); a3 = fmaf(x0, W3[0 * 64 + c], a3);
    a0 = fmaf(x1, W0[1 * 64 + c], a0); a1 = fmaf(x1, W1[1 * 64 + c], a1);
    a2 = fmaf(x1, W2[1 * 64 + c], a2); a3 = fmaf(x1, W3[1 * 64 + c], a3);
    a0 = fmaf(x2, W0[2 * 64 + c], a0); a1 = fmaf(x2, W1[2 * 64 + c], a1);
    a2 = fmaf(x2, W2[2 * 64 + c], a2); a3 = fmaf(x2, W3[2 * 64 + c], a3);
    a0 = fmaf(x3, W0[3 * 64 + c], a0); a1 = fmaf(x3, W1[3 * 64 + c], a1);
    a2 = fmaf(x3, W2[3 * 64 + c], a2); a3 = fmaf(x3, W3[3 * 64 + c], a3);
    a0 = fmaf(x4, W0[4 * 64 + c], a0); a1 = fmaf(x4, W1[4 * 64 + c], a1);
    a2 = fmaf(x4, W2[4 * 64 + c], a2); a3 = fmaf(x4, W3[4 * 64 + c], a3);
    a0 = fmaf(x5, W0[5 * 64 + c], a0); a1 = fmaf(x5, W1[5 * 64 + c], a1);
    a2 = fmaf(x5, W2[5 * 64 + c], a2); a3 = fmaf(x5, W3[5 * 64 + c], a3);
    out0[t] = __float2half(a0);
    out1[t] = __float2half(a1);
    out2[t] = __float2half(a2);
    out3[t] = __float2half(a3);
  }
}

// ---------------- quarter-wave GAT machinery ----------------
template <int R0>
__device__ __forceinline__ float redsum(float ee) {
  #pragma unroll
  for (int off = R0; off > 0; off >>= 1) ee += __shfl_xor(ee, off, 64);
  return ee;
}

__device__ __forceinline__ float4 cvt_h(int2 r) {
  __half2 ab = *(__half2*)&r.x;
  __half2 cd = *(__half2*)&r.y;
  float2 f0 = __half22float2(ab);
  float2 f1 = __half22float2(cd);
  return make_float4(f0.x, f0.y, f1.x, f1.y);
}
__device__ __forceinline__ float4 ldrow_h(const __half* p) { return cvt_h(*(const int2*)p); }

__device__ __forceinline__ void merge_groups(float& s, float4& a) {
  s   += __shfl_xor(s, 16, 64);
  a.x += __shfl_xor(a.x, 16, 64);
  a.y += __shfl_xor(a.y, 16, 64);
  a.z += __shfl_xor(a.z, 16, 64);
  a.w += __shfl_xor(a.w, 16, 64);
  s   += __shfl_xor(s, 32, 64);
  a.x += __shfl_xor(a.x, 32, 64);
  a.y += __shfl_xor(a.y, 32, 64);
  a.z += __shfl_xor(a.z, 32, 64);
  a.w += __shfl_xor(a.w, 32, 64);
}

template <int R0>
__device__ __forceinline__ void edge_acc(float4 p4, bool ok, float4 h, float4 a,
                                         float& s, float4& acc) {
  float vx = p4.x + h.x; vx = fmaxf(vx, 0.2f * vx);
  float vy = p4.y + h.y; vy = fmaxf(vy, 0.2f * vy);
  float vz = p4.z + h.z; vz = fmaxf(vz, 0.2f * vz);
  float vw = p4.w + h.w; vw = fmaxf(vw, 0.2f * vw);
  float ee = redsum<R0>(fmaf(vx, a.x, fmaf(vy, a.y, fmaf(vz, a.z, vw * a.w))));
  float w = ok ? __expf(ee) : 0.f;
  s += w;
  acc.x = fmaf(w, p4.x, acc.x);
  acc.y = fmaf(w, p4.y, acc.y);
  acc.z = fmaf(w, p4.z, acc.z);
  acc.w = fmaf(w, p4.w, acc.w);
}

template <int CHUNK, int NSLOT, int R0, bool MASK>
__device__ __forceinline__ void gat4_table(unsigned beg, unsigned end, unsigned slot,
                                           const int* __restrict__ srcs,
                                           const __half* __restrict__ tab, int q, int d,
                                           float4 h, float4 a, float& s, float4& acc) {
  for (unsigned i = beg + slot; i < end; i += NSLOT * CHUNK) {
    float4 p[CHUNK]; bool ok[CHUNK];
    #pragma unroll
    for (int j = 0; j < CHUNK; ++j) {
      unsigned idx = i + (unsigned)(j * NSLOT);
      int sv = (idx < end) ? srcs[idx] : 0;
      ok[j] = (idx < end) && (!MASK || sv != d);
      p[j] = ldrow_h(tab + (size_t)sv * 64 + 4 * q);
    }
    #pragma unroll
    for (int j = 0; j < CHUNK; ++j) edge_acc<R0>(p[j], ok[j], h, a, s, acc);
  }
}

// ---------------- layer 1 (heads=2; 4-deep cross-dst src prefetch) ---------
__global__ __launch_bounds__(256)
void l1_all_kernel(const unsigned* __restrict__ rp_all, const int* __restrict__ src_all,
                   const __half* __restrict__ TA, const __half* __restrict__ TB,
                   const __half* __restrict__ HRVV, const __half* __restrict__ HRIV,
                   const float* __restrict__ x_rsu,
                   const float* __restrict__ Wl_iv, const float* __restrict__ bl_iv,
                   const float* __restrict__ att_vv, const float* __restrict__ att_iv,
                   const float* __restrict__ Wr_vi, const float* __restrict__ br_vi,
                   const float* __restrict__ att_vi,
                   const float* __restrict__ b_vv, const float* __restrict__ b_iv,
                   const float* __restrict__ b_vi,
                   float* __restrict__ ACCV, float* __restrict__ ACCR) {
  __shared__ float sS[4][64];
  __shared__ float4 sA[4][64];
  int tid = threadIdx.x, lane = tid & 63, wid = tid >> 6;
  int q = lane & 15, g = lane >> 4;
  if (blockIdx.x < GBV) {
    float4 av = *(const float4*)&att_vv[4 * q];
    float4 ai = *(const float4*)&att_iv[4 * q];
    float4 wli = *(const float4*)&Wl_iv[4 * q];
    float4 bli = *(const float4*)&bl_iv[4 * q];
    float4 bvv = *(const float4*)&b_vv[4 * q];
    float4 biv = *(const float4*)&b_iv[4 * q];
    float4 bb = make_float4(bvv.x + biv.x, bvv.y + biv.y, bvv.z + biv.z, bvv.w + biv.w);
    const int* src_iv = src_all + EVV + EVI;
    int d = blockIdx.x * 4 + wid;
    unsigned vb = 0, ve = 0, ib = 0, ie = 0;
    int psv0 = 0, psv1 = 0, psv2 = 0, psv3 = 0, pisv = 0;
    if (d < NV) {
      vb = rp_all[RB_VV + d]; ve = rp_all[RB_VV + d + 1];
      ib = rp_all[RB_IV + d]; ie = rp_all[RB_IV + d + 1];
      unsigned i0 = vb + (unsigned)g;
      psv0 = (i0 < ve) ? src_all[i0] : 0;
      psv1 = (i0 + 4 < ve) ? src_all[i0 + 4] : 0;
      psv2 = (i0 + 8 < ve) ? src_all[i0 + 8] : 0;
      psv3 = (i0 + 12 < ve) ? src_all[i0 + 12] : 0;
      unsigned ii0 = ib + (unsigned)g;
      pisv = (ii0 < ie) ? src_iv[ii0] : 0;
    }
    while (d < NV) {
      int dn = d + GBV * 4;
      unsigned cvb = vb, cve = ve, cib = ib, cie = ie;
      int2 r0raw = *(const int2*)(TA + (size_t)psv0 * 64 + 4 * q);
      int2 r1raw = *(const int2*)(TA + (size_t)psv1 * 64 + 4 * q);
      int2 r2raw = *(const int2*)(TA + (size_t)psv2 * 64 + 4 * q);
      int2 r3raw = *(const int2*)(TA + (size_t)psv3 * 64 + 4 * q);
      float ixv = x_rsu[pisv];
      bool iok0 = (cib + (unsigned)g) < cie;
      if (dn < NV) {
        vb = rp_all[RB_VV + dn]; ve = rp_all[RB_VV + dn + 1];
        ib = rp_all[RB_IV + dn]; ie = rp_all[RB_IV + dn + 1];
      }
      float4 hv = ldrow_h(HRVV + (size_t)d * 64 + 4 * q);
      float4 hi = ldrow_h(HRIV + (size_t)d * 64 + 4 * q);
      float sv_ = 0.f; float4 av_ = make_float4(0.f, 0.f, 0.f, 0.f);
      edge_acc<4>(cvt_h(r0raw), (cvb + (unsigned)g) < cve, hv, av, sv_, av_);
      edge_acc<4>(cvt_h(r1raw), (cvb + (unsigned)g + 4) < cve, hv, av, sv_, av_);
      edge_acc<4>(cvt_h(r2raw), (cvb + (unsigned)g + 8) < cve, hv, av, sv_, av_);
      edge_acc<4>(cvt_h(r3raw), (cvb + (unsigned)g + 12) < cve, hv, av, sv_, av_);
      gat4_table<2, 4, 4, false>(cvb + 16, cve, (unsigned)g, src_all, TA, q, d, hv, av, sv_, av_);
      if (g == 0) {
        float4 p4 = ldrow_h(TA + (size_t)d * 64 + 4 * q);
        edge_acc<4>(p4, true, hv, av, sv_, av_);
      }
      merge_groups(sv_, av_);
      float si_ = 0.f; float4 ai_ = make_float4(0.f, 0.f, 0.f, 0.f);
      {
        float4 p4;
        p4.x = fmaf(ixv, wli.x, bli.x);
        p4.y = fmaf(ixv, wli.y, bli.y);
        p4.z = fmaf(ixv, wli.z, bli.z);
        p4.w = fmaf(ixv, wli.w, bli.w);
        edge_acc<4>(p4, iok0, hi, ai, si_, ai_);
      }
      for (unsigned i = cib + 4 + (unsigned)g; i < cie; i += 4) {
        int sv2 = src_iv[i];
        float xv2 = x_rsu[sv2];
        float4 p4;
        p4.x = fmaf(xv2, wli.x, bli.x);
        p4.y = fmaf(xv2, wli.y, bli.y);
        p4.z = fmaf(xv2, wli.z, bli.z);
        p4.w = fmaf(xv2, wli.w, bli.w);
        edge_acc<4>(p4, true, hi, ai, si_, ai_);
      }
      merge_groups(si_, ai_);
      if (dn < NV) {
        unsigned i0 = vb + (unsigned)g;
        psv0 = (i0 < ve) ? src_all[i0] : 0;
        psv1 = (i0 + 4 < ve) ? src_all[i0 + 4] : 0;
        psv2 = (i0 + 8 < ve) ? src_all[i0 + 8] : 0;
        psv3 = (i0 + 12 < ve) ? src_all[i0 + 12] : 0;
        unsigned ii0 = ib + (unsigned)g;
        pisv = (ii0 < ie) ? src_iv[ii0] : 0;
      }
      if (g == 0) {
        float rv = 1.f / (sv_ + 1e-16f), ri = 1.f / (si_ + 1e-16f);
        float v0 = av_.x * rv + ai_.x * ri + bb.x;
        float v1 = av_.y * rv + ai_.y * ri + bb.y;
        float v2 = av_.z * rv + ai_.z * ri + bb.z;
        float v3 = av_.w * rv + ai_.w * ri + bb.w;
        float4 o;
        o.x = (v0 > 0.f) ? v0 : expm1f(v0);
        o.y = (v1 > 0.f) ? v1 : expm1f(v1);
        o.z = (v2 > 0.f) ? v2 : expm1f(v2);
        o.w = (v3 > 0.f) ? v3 : expm1f(v3);
        *(float4*)&ACCV[(size_t)d * 64 + 4 * q] = o;
      }
      d = dn;
    }
  } else {
    int d = (int)blockIdx.x - GBV;
    float xv = x_rsu[d];
    float4 wrv = *(const float4*)&Wr_vi[4 * q];
    float4 brv = *(const float4*)&br_vi[4 * q];
    float4 h;
    h.x = fmaf(xv, wrv.x, brv.x);
    h.y = fmaf(xv, wrv.y, brv.y);
    h.z = fmaf(xv, wrv.z, brv.z);
    h.w = fmaf(xv, wrv.w, brv.w);
    float4 a = *(const float4*)&att_vi[4 * q];
    float s_ = 0.f; float4 a_ = make_float4(0.f, 0.f, 0.f, 0.f);
    gat4_table<4, 16, 4, false>(rp_all[RB_VI + d], rp_all[RB_VI + d + 1],
                                (unsigned)(wid * 4 + g), src_all + EVV, TB, q, d,
                                h, a, s_, a_);
    merge_groups(s_, a_);
    if (wid != 0) { sS[wid][lane] = s_; sA[wid][lane] = a_; }
    __syncthreads();
    if (wid == 0) {
      #pragma unroll
      for (int w2 = 1; w2 < 4; ++w2) {
        s_ += sS[w2][lane];
        float4 t = sA[w2][lane];
        a_.x += t.x; a_.y += t.y; a_.z += t.z; a_.w += t.w;
      }
      if (g == 0) {
        float4 bvi = *(const float4*)&b_vi[4 * q];
        float inv = 1.f / (s_ + 1e-16f);
        float v0 = a_.x * inv + bvi.x;
        float v1 = a_.y * inv + bvi.y;
        float v2 = a_.z * inv + bvi.z;
        float v3 = a_.w * inv + bvi.w;
        float4 o;
        o.x = (v0 > 0.f) ? v0 : expm1f(v0);
        o.y = (v1 > 0.f) ? v1 : expm1f(v1);
        o.z = (v2 > 0.f) ? v2 : expm1f(v2);
        o.w = (v3 > 0.f) ? v3 : expm1f(v3);
        *(float4*)&ACCR[(size_t)d * 64 + 4 * q] = o;
      }
    }
  }
}

// ---------------- layer-2 projections: quad (veh) + dual (rsu); fp16 hl AND hr ----------
__global__ __launch_bounds__(256, 2)
void quad_proj_kernel(const float* __restrict__ ACCVin, const float* __restrict__ ACCR,
                      const float* __restrict__ W0, const float* __restrict__ b0,
                      const float* __restrict__ W1, const float* __restrict__ b1,
                      const float* __restrict__ W2, const float* __restrict__ b2,
                      const float* __restrict__ W3, const float* __restrict__ b3,
                      const float* __restrict__ W4, const float* __restrict__ b4,
                      const float* __restrict__ W5, const float* __restrict__ b5,
                      __half* __restrict__ O0, __half* __restrict__ O1,
                      __half* __restrict__ O2, __half* __restrict__ O3,
                      __half* __restrict__ S0o, float* __restrict__ S1o) {
  __shared__ float w0s[4096], w1s[4096], w2s[4096], w3s[4096], xtile[2048];
  int t = threadIdx.x;
  bool vehb = blockIdx.x < NBQ;
  const float* X = vehb ? ACCVin : ACCR;
  int n = vehb ? NV : NR;
  int base = (vehb ? (int)blockIdx.x : (int)blockIdx.x - NBQ) * 32;
  if (vehb) {
    for (int i = t; i < 4096; i += 256) { w0s[i] = W0[i]; w1s[i] = W1[i]; w2s[i] = W2[i]; w3s[i] = W3[i]; }
  } else {
    for (int i = t; i < 4096; i += 256) { w0s[i] = W4[i]; w1s[i] = W5[i]; }
  }
  for (int i = t; i < 2048; i += 256) {
    int row = base + (i >> 6);
    int rc = (row < n) ? row : (n - 1);
    xtile[i] = X[(size_t)rc * 64 + (i & 63)];
  }
  __syncthreads();
  int lane = t & 63, wid = t >> 6;
  int wr = wid * 8;
  int p = 4 * (lane & 15) + (lane >> 4);
  if (vehb) {
    float a0[8], a1[8], a2[8], a3[8];
    #pragma unroll
    for (int r = 0; r < 8; ++r) { a0[r] = 0.f; a1[r] = 0.f; a2[r] = 0.f; a3[r] = 0.f; }
    for (int kq = 0; kq < 16; ++kq) {
      int k = kq * 4;
      float u00 = w0s[(k + 0) * 64 + lane], u01 = w0s[(k + 1) * 64 + lane];
      float u02 = w0s[(k + 2) * 64 + lane], u03 = w0s[(k + 3) * 64 + lane];
      float u10 = w1s[(k + 0) * 64 + lane], u11 = w1s[(k + 1) * 64 + lane];
      float u12 = w1s[(k + 2) * 64 + lane], u13 = w1s[(k + 3) * 64 + lane];
      float u20 = w2s[(k + 0) * 64 + lane], u21 = w2s[(k + 1) * 64 + lane];
      float u22 = w2s[(k + 2) * 64 + lane], u23 = w2s[(k + 3) * 64 + lane];
      float u30 = w3s[(k + 0) * 64 + lane], u31 = w3s[(k + 1) * 64 + lane];
      float u32 = w3s[(k + 2) * 64 + lane], u33 = w3s[(k + 3) * 64 + lane];
      #pragma unroll
      for (int r = 0; r < 8; ++r) {
        float4 xv = *(const float4*)&xtile[(wr + r) * 64 + k];
        a0[r] = fmaf(xv.x, u00, a0[r]); a0[r] = fmaf(xv.y, u01, a0[r]);
        a0[r] = fmaf(xv.z, u02, a0[r]); a0[r] = fmaf(xv.w, u03, a0[r]);
        a1[r] = fmaf(xv.x, u10, a1[r]); a1[r] = fmaf(xv.y, u11, a1[r]);
        a1[r] = fmaf(xv.z, u12, a1[r]); a1[r] = fmaf(xv.w, u13, a1[r]);
        a2[r] = fmaf(xv.x, u20, a2[r]); a2[r] = fmaf(xv.y, u21, a2[r]);
        a2[r] = fmaf(xv.z, u22, a2[r]); a2[r] = fmaf(xv.w, u23, a2[r]);
        a3[r] = fmaf(xv.x, u30, a3[r]); a3[r] = fmaf(xv.y, u31, a3[r]);
        a3[r] = fmaf(xv.z, u32, a3[r]); a3[r] = fmaf(xv.w, u33, a3[r]);
      }
    }
    float c0 = b0[lane], c1 = b1[lane], c2 = b2[lane], c3 = b3[lane];
    #pragma unroll
    for (int r = 0; r < 8; ++r) {
      int row = base + wr + r;
      if (row < n) {
        O0[(size_t)row * 64 + p] = __float2half(a0[r] + c0);
        O1[(size_t)row * 64 + p] = __float2half(a1[r] + c1);
        O2[(size_t)row * 64 + p] = __float2half(a2[r] + c2);
        O3[(size_t)row * 64 + p] = __float2half(a3[r] + c3);
      }
    }
  } else {
    float a0[8], a1[8];
    #pragma unroll
    for (int r = 0; r < 8; ++r) { a0[r] = 0.f; a1[r] = 0.f; }
    for (int kq = 0; kq < 16; ++kq) {
      int k = kq * 4;
      float u00 = w0s[(k + 0) * 64 + lane], u01 = w0s[(k + 1) * 64 + lane];
      float u02 = w0s[(k + 2) * 64 + lane], u03 = w0s[(k + 3) * 64 + lane];
      float u10 = w1s[(k + 0) * 64 + lane], u11 = w1s[(k + 1) * 64 + lane];
      float u12 = w1s[(k + 2) * 64 + lane], u13 = w1s[(k + 3) * 64 + lane];
      #pragma unroll
      for (int r = 0; r < 8; ++r) {
        float4 xv = *(const float4*)&xtile[(wr + r) * 64 + k];
        a0[r] = fmaf(xv.x, u00, a0[r]); a0[r] = fmaf(xv.y, u01, a0[r]);
        a0[r] = fmaf(xv.z, u02, a0[r]); a0[r] = fmaf(xv.w, u03, a0[r]);
        a1[r] = fmaf(xv.x, u10, a1[r]); a1[r] = fmaf(xv.y, u11, a1[r]);
        a1[r] = fmaf(xv.z, u12, a1[r]); a1[r] = fmaf(xv.w, u13, a1[r]);
      }
    }
    float c0 = b4[lane], c1 = b5[lane];
    #pragma unroll
    for (int r = 0; r < 8; ++r) {
      int row = base + wr + r;
      if (row < n) {
        S0o[(size_t)row * 64 + p] = __float2half(a0[r] + c0);
        S1o[(size_t)row * 64 + p] = a1[r] + c1;
      }
    }
  }
}

// ---------------- layer 2 (heads=1; 4-deep cross-dst src prefetch) ----------------------
__global__ __launch_bounds__(256)
void l2_all_kernel(const unsigned* __restrict__ rp_all, const int* __restrict__ src_all,
                   const __half* __restrict__ Tvvl, const __half* __restrict__ Tvvr,
                   const __half* __restrict__ Tivl, const __half* __restrict__ Tivr,
                   const __half* __restrict__ Tvil, const float* __restrict__ Tvir,
                   const float* __restrict__ att_vv, const float* __restrict__ att_iv,
                   const float* __restrict__ att_vi,
                   const float* __restrict__ b_vv, const float* __restrict__ b_iv,
                   const float* __restrict__ b_vi,
                   const float* __restrict__ lnv_w, const float* __restrict__ lnv_b,
                   const float* __restrict__ lnr_w, const float* __restrict__ lnr_b,
                   float* __restrict__ outv, float* __restrict__ outr) {
  __shared__ float sS[4][64];
  __shared__ float4 sA[4][64];
  int tid = threadIdx.x, lane = tid & 63, wid = tid >> 6;
  int q = lane & 15, g = lane >> 4;
  if (blockIdx.x < GBV) {
    float4 av = make_float4(att_vv[q], att_vv[q + 16], att_vv[q + 32], att_vv[q + 48]);
    float4 ai = make_float4(att_iv[q], att_iv[q + 16], att_iv[q + 32], att_iv[q + 48]);
    float4 bb = make_float4(b_vv[q] + b_iv[q], b_vv[q + 16] + b_iv[q + 16],
                            b_vv[q + 32] + b_iv[q + 32], b_vv[q + 48] + b_iv[q + 48]);
    float4 lw = make_float4(lnv_w[q], lnv_w[q + 16], lnv_w[q + 32], lnv_w[q + 48]);
    float4 lb = make_float4(lnv_b[q], lnv_b[q + 16], lnv_b[q + 32], lnv_b[q + 48]);
    const int* src_iv = src_all + EVV + EVI;
    int d = blockIdx.x * 4 + wid;
    unsigned vb = 0, ve = 0, ib = 0, ie = 0;
    int psv0 = 0, psv1 = 0, psv2 = 0, psv3 = 0, pisv = 0;
    if (d < NV) {
      vb = rp_all[RB_VV + d]; ve = rp_all[RB_VV + d + 1];
      ib = rp_all[RB_IV + d]; ie = rp_all[RB_IV + d + 1];
      unsigned i0 = vb + (unsigned)g;
      psv0 = (i0 < ve) ? src_all[i0] : 0;
      psv1 = (i0 + 4 < ve) ? src_all[i0 + 4] : 0;
      psv2 = (i0 + 8 < ve) ? src_all[i0 + 8] : 0;
      psv3 = (i0 + 12 < ve) ? src_all[i0 + 12] : 0;
      unsigned ii0 = ib + (unsigned)g;
      pisv = (ii0 < ie) ? src_iv[ii0] : 0;
    }
    while (d < NV) {
      int dn = d + GBV * 4;
      unsigned cvb = vb, cve = ve, cib = ib, cie = ie;
      int cisv = pisv;
      int2 r0raw = *(const int2*)(Tvvl + (size_t)psv0 * 64 + 4 * q);
      int2 r1raw = *(const int2*)(Tvvl + (size_t)psv1 * 64 + 4 * q);
      int2 r2raw = *(const int2*)(Tvvl + (size_t)psv2 * 64 + 4 * q);
      int2 r3raw = *(const int2*)(Tvvl + (size_t)psv3 * 64 + 4 * q);
      int2 ipraw = *(const int2*)(Tivl + (size_t)cisv * 64 + 4 * q);
      bool iok0 = (cib + (unsigned)g) < cie;
      if (dn < NV) {
        vb = rp_all[RB_VV + dn]; ve = rp_all[RB_VV + dn + 1];
        ib = rp_all[RB_IV + dn]; ie = rp_all[RB_IV + dn + 1];
      }
      float4 hv = ldrow_h(Tvvr + (size_t)d * 64 + 4 * q);
      float4 hi = ldrow_h(Tivr + (size_t)d * 64 + 4 * q);
      float sv_ = 0.f; float4 av_ = make_float4(0.f, 0.f, 0.f, 0.f);
      edge_acc<8>(cvt_h(r0raw), (cvb + (unsigned)g) < cve, hv, av, sv_, av_);
      edge_acc<8>(cvt_h(r1raw), (cvb + (unsigned)g + 4) < cve, hv, av, sv_, av_);
      edge_acc<8>(cvt_h(r2raw), (cvb + (unsigned)g + 8) < cve, hv, av, sv_, av_);
      edge_acc<8>(cvt_h(r3raw), (cvb + (unsigned)g + 12) < cve, hv, av, sv_, av_);
      gat4_table<2, 4, 8, false>(cvb + 16, cve, (unsigned)g, src_all, Tvvl, q, d, hv, av, sv_, av_);
      if (g == 0) {
        float4 p4 = ldrow_h(Tvvl + (size_t)d * 64 + 4 * q);
        edge_acc<8>(p4, true, hv, av, sv_, av_);
      }
      merge_groups(sv_, av_);
      float si_ = 0.f; float4 ai_ = make_float4(0.f, 0.f, 0.f, 0.f);
      edge_acc<8>(cvt_h(ipraw), iok0 && (cisv != d), hi, ai, si_, ai_);
      for (unsigned i = cib + 4 + (unsigned)g; i < cie; i += 4) {
        int sv2 = src_iv[i];
        float4 p4 = ldrow_h(Tivl + (size_t)sv2 * 64 + 4 * q);
        edge_acc<8>(p4, sv2 != d, hi, ai, si_, ai_);
      }
      if (g == 0 && d < NR) {
        float4 p4 = ldrow_h(Tivl + (size_t)d * 64 + 4 * q);
        edge_acc<8>(p4, true, hi, ai, si_, ai_);
      }
      merge_groups(si_, ai_);
      if (dn < NV) {
        unsigned i0 = vb + (unsigned)g;
        psv0 = (i0 < ve) ? src_all[i0] : 0;
        psv1 = (i0 + 4 < ve) ? src_all[i0 + 4] : 0;
        psv2 = (i0 + 8 < ve) ? src_all[i0 + 8] : 0;
        psv3 = (i0 + 12 < ve) ? src_all[i0 + 12] : 0;
        unsigned ii0 = ib + (unsigned)g;
        pisv = (ii0 < ie) ? src_iv[ii0] : 0;
      }
      float rv = 1.f / (sv_ + 1e-16f), ri = 1.f / (si_ + 1e-16f);
      float v0 = av_.x * rv + ai_.x * ri + bb.x;
      float v1 = av_.y * rv + ai_.y * ri + bb.y;
      float v2 = av_.z * rv + ai_.z * ri + bb.z;
      float v3 = av_.w * rv + ai_.w * ri + bb.w;
      float sum = redsum<8>(v0 + v1 + v2 + v3);
      float mu = sum * (1.f / 64.f);
      float d0 = v0 - mu, d1 = v1 - mu, d2 = v2 - mu, d3 = v3 - mu;
      float qq = redsum<8>(d0 * d0 + d1 * d1 + d2 * d2 + d3 * d3);
      float is = rsqrtf(qq * (1.f / 64.f) + 1e-5f);
      if (g == 0) {
        outv[(size_t)d * 64 + q]      = d0 * is * lw.x + lb.x;
        outv[(size_t)d * 64 + q + 16] = d1 * is * lw.y + lb.y;
        outv[(size_t)d * 64 + q + 32] = d2 * is * lw.z + lb.z;
        outv[(size_t)d * 64 + q + 48] = d3 * is * lw.w + lb.w;
      }
      d = dn;
    }
  } else {
    int d = (int)blockIdx.x - GBV;
    float4 h = *(const float4*)&Tvir[(size_t)d * 64 + 4 * q];
    float4 a = make_float4(att_vi[q], att_vi[q + 16], att_vi[q + 32], att_vi[q + 48]);
    float s_ = 0.f; float4 a_ = make_float4(0.f, 0.f, 0.f, 0.f);
    gat4_table<4, 16, 8, true>(rp_all[RB_VI + d], rp_all[RB_VI + d + 1],
                               (unsigned)(wid * 4 + g), src_all + EVV, Tvil, q, d,
                               h, a, s_, a_);
    if (wid == 0 && g == 0) {
      float4 p4 = ldrow_h(Tvil + (size_t)d * 64 + 4 * q);
      edge_acc<8>(p4, true, h, a, s_, a_);
    }
    merge_groups(s_, a_);
    if (wid != 0) { sS[wid][lane] = s_; sA[wid][lane] = a_; }
    __syncthreads();
    if (wid == 0) {
      #pragma unroll
      for (int w2 = 1; w2 < 4; ++w2) {
        s_ += sS[w2][lane];
        float4 t = sA[w2][lane];
        a_.x += t.x; a_.y += t.y; a_.z += t.z; a_.w += t.w;
      }
      float inv = 1.f / (s_ + 1e-16f);
      float v0 = a_.x * inv + b_vi[q];
      float v1 = a_.y * inv + b_vi[q + 16];
      float v2 = a_.z * inv + b_vi[q + 32];
      float v3 = a_.w * inv + b_vi[q + 48];
      float sum = redsum<8>(v0 + v1 + v2 + v3);
      float mu = sum * (1.f / 64.f);
      float d0 = v0 - mu, d1 = v1 - mu, d2 = v2 - mu, d3 = v3 - mu;
      float qq = redsum<8>(d0 * d0 + d1 * d1 + d2 * d2 + d3 * d3);
      float is = rsqrtf(qq * (1.f / 64.f) + 1e-5f);
      if (g == 0) {
        outr[(size_t)d * 64 + q]      = d0 * is * lnr_w[q] + lnr_b[q];
        outr[(size_t)d * 64 + q + 16] = d1 * is * lnr_w[q + 16] + lnr_b[q + 16];
        outr[(size_t)d * 64 + q + 32] = d2 * is * lnr_w[q + 32] + lnr_b[q + 32];
        outr[(size_t)d * 64 + q + 48] = d3 * is * lnr_w[q + 48] + lnr_b[q + 48];
      }
    }
  }
}

extern "C" void kernel_launch(void* const* d_in, const int* in_sizes, int n_in,
                              void* d_out, int out_size, void* d_ws, size_t ws_size,
                              hipStream_t stream) {
  const float* x_veh = (const float*)d_in[0];
  const float* x_rsu = (const float*)d_in[1];
  const int* ei_v2v = (const int*)d_in[2];
  const int* ei_v2i = (const int*)d_in[3];
  const int* ei_i2v = (const int*)d_in[4];
  const float* P[36];
  for (int i = 0; i < 36; ++i) P[i] = (const float*)d_in[5 + i];
  const float* lnv_w = (const float*)d_in[41];
  const float* lnv_b = (const float*)d_in[42];
  const float* lnr_w = (const float*)d_in[43];
  const float* lnr_b = (const float*)d_in[44];

  float* ws = (float*)d_ws;
  float* P0    = ws;                   // L1: HRIV_h | L2: Tvvl_h + Tvil_h
  float* P1    = P0 + 3200000;         // L1: HRVV_h | L2: Tvvr_h
  float* ACCV  = P1 + 3200000;         // CSR build: cnt_rep+roff | h_veh f32 after l1
  float* ACC2V = ACCV + 3200000;       // L1: TA_h + TB_h | L2: Tivr_h
  float* S0    = ACC2V + 3200000;      // L2: Tivl_h (rsu, half)
  float* S1    = S0 + 32000;           // L2: Tvir f32 (rsu)
  float* ACCR  = S1 + 32000;           // h_rsu f32
  unsigned* rp_all     = (unsigned*)(ACCR + 32000);
  unsigned* tsum       = rp_all + RP_LEN;
  unsigned* rank_all   = tsum + 128;
  int* src_all         = (int*)(rank_all + 600000);
  unsigned* cnt_rep    = (unsigned*)ACCV;
  unsigned* roff       = cnt_rep + NREP * CNT_LEN;
  __half* TA_h   = (__half*)ACC2V;
  __half* TB_h   = (__half*)(ACC2V + 1600000);
  __half* HRVV_h = (__half*)P1;
  __half* HRIV_h = (__half*)P0;
  __half* Tvvl_h = (__half*)P0;
  __half* Tvil_h = (__half*)(P0 + 1600000);
  __half* Tvvr_h = (__half*)P1;
  __half* Tivr_h = (__half*)ACC2V;
  __half* Tivl_h = (__half*)S0;

  // ---- CSR build (XCD-local replicated counters) + layer-1 tables ----
  hipMemsetAsync(cnt_rep, 0, (size_t)NREP * CNT_LEN * 4, stream);
  hist_all_kernel<<<HB1, 256, 0, stream>>>(
      ei_v2v, ei_v2v + EVV, ei_v2i + EVI, ei_i2v + EIV, cnt_rep, rank_all);
  tilesum_kernel<<<T_TOT, 256, 0, stream>>>(cnt_rep, tsum);
  scanwrite_kernel<<<T_TOT, 256, 0, stream>>>(cnt_rep, tsum, rp_all, roff);
  fill_proj_kernel<<<FB4 + PB, 256, 0, stream>>>(
      ei_v2v, ei_v2v + EVV, ei_v2i, ei_v2i + EVI, ei_i2v, ei_i2v + EIV,
      rp_all, roff, rank_all, src_all,
      x_veh, P[0], P[1], P[6], P[7], P[2], P[3], P[14], P[15],
      TA_h, TB_h, HRVV_h, HRIV_h);

  // ---- layer 1 ----
  l1_all_kernel<<<GBV + NR, 256, 0, stream>>>(
      rp_all, src_all, TA_h, TB_h, HRVV_h, HRIV_h, x_rsu,
      P[12], P[13],
      P[4], P[16],
      P[8], P[9], P[10],
      P[5], P[17], P[11],
      ACCV, ACCR);

  // ---- layer-2 projections ----
  quad_proj_kernel<<<NBQ + RSB, 256, 0, stream>>>(
      ACCV, ACCR,
      P[18], P[19],
      P[20], P[21],
      P[32], P[33],
      P[24], P[25],
      P[30], P[31],
      P[26], P[27],
      Tvvl_h, Tvvr_h, Tivr_h, Tvil_h, Tivl_h, S1);

  // ---- layer 2 ----
  l2_all_kernel<<<GBV + NR, 256, 0, stream>>>(
      rp_all, src_all,
      Tvvl_h, Tvvr_h, Tivl_h, Tivr_h, Tvil_h, S1,
      P[22], P[34], P[28],
      P[23], P[35], P[29],
      lnv_w, lnv_b, lnr_w, lnr_b,
      (float*)d_out, (float*)d_out + (size_t)NV * 64);
}

// Round 24
// 209.075 us; speedup vs baseline: 1.0418x; 1.0418x over previous
//
#include <hip/hip_runtime.h>
#include <hip/hip_fp16.h>
#include <math.h>
#include <float.h>

#define NV 50000
#define NR 500
#define EVV 400000
#define EVI 100000
#define EIV 100000

#define CB_VV 0
#define CB_VI 50000
#define CB_IV 50500
#define CNT_LEN 100500
#define NREP 8
#define RB_VV 0
#define RB_VI 50004
#define RB_IV 50508
#define RP_LEN 100512
#define TILE 1024
#define T_VV 49
#define T_IV 49
#define T_TOT 99
#define HB1 2344
#define FB4 586
#define PB 12500
#define GBV 2048
#define NBQ 1563
#define RSB 16

// ---------------- hist: 1 edge/thread, XCD-local replicated counters ----------------
__global__ void hist_all_kernel(const int* __restrict__ vv_s, const int* __restrict__ vv_d,
                                const int* __restrict__ vi_d, const int* __restrict__ iv_d,
                                unsigned* __restrict__ cnt_rep, unsigned* __restrict__ rank_all) {
  int e = blockIdx.x * 256 + threadIdx.x;
  unsigned rbase = (unsigned)(blockIdx.x & (NREP - 1)) * CNT_LEN;
  if (e < EVV) {
    int s = vv_s[e], d = vv_d[e];
    if (s != d) rank_all[e] = atomicAdd(&cnt_rep[rbase + CB_VV + d], 1u);
  } else if (e < EVV + EVI) {
    rank_all[e] = atomicAdd(&cnt_rep[rbase + CB_VI + vi_d[e - EVV]], 1u);
  } else if (e < EVV + EVI + EIV) {
    rank_all[e] = atomicAdd(&cnt_rep[rbase + CB_IV + iv_d[e - EVV - EVI]], 1u);
  }
}

__device__ __forceinline__ void tile_decode(int b, int& cb, int& rb, int& n, int& base,
                                            int& topo, int& lt) {
  topo = (b < T_VV) ? 0 : (b == T_VV) ? 1 : 2;
  lt   = (topo == 0) ? b : (topo == 1) ? 0 : b - T_VV - 1;
  cb   = (topo == 0) ? CB_VV : (topo == 1) ? CB_VI : CB_IV;
  rb   = (topo == 0) ? RB_VV : (topo == 1) ? RB_VI : RB_IV;
  n    = (topo == 1) ? NR : NV;
  base = lt * TILE;
}

__global__ void tilesum_kernel(const unsigned* __restrict__ cnt_rep, unsigned* __restrict__ tsum) {
  int cb, rb, n, base, topo, lt;
  tile_decode(blockIdx.x, cb, rb, n, base, topo, lt);
  int t = threadIdx.x, lane = t & 63, wid = t >> 6;
  unsigned s = 0;
  #pragma unroll
  for (int j = 0; j < 4; ++j) {
    int i = base + t + j * 256;
    if (i < n) {
      #pragma unroll
      for (int r = 0; r < NREP; ++r) s += cnt_rep[r * CNT_LEN + cb + i];
    }
  }
  #pragma unroll
  for (int off = 32; off > 0; off >>= 1) s += (unsigned)__shfl_xor((int)s, off, 64);
  __shared__ unsigned wt[4];
  if (lane == 0) wt[wid] = s;
  __syncthreads();
  if (t == 0) tsum[blockIdx.x] = wt[0] + wt[1] + wt[2] + wt[3];
}

__global__ void scanwrite_kernel(const unsigned* __restrict__ cnt_rep,
                                 const unsigned* __restrict__ tsum,
                                 unsigned* __restrict__ rp_all,
                                 unsigned* __restrict__ roff) {
  int cb, rb, n, base, topo, lt;
  tile_decode(blockIdx.x, cb, rb, n, base, topo, lt);
  int t = threadIdx.x, lane = t & 63, wid = t >> 6;
  __shared__ unsigned sprefix;
  __shared__ unsigned wt[4];
  if (wid == 0) {
    int first = (topo == 0) ? 0 : (topo == 1) ? T_VV : T_VV + 1;
    int cntT  = (topo == 1) ? 1 : T_VV;
    unsigned tv = (lane < cntT) ? tsum[first + lane] : 0u;
    unsigned vp = (lane < lt) ? tv : 0u;
    unsigned vt = tv;
    #pragma unroll
    for (int off = 32; off > 0; off >>= 1) {
      vp += (unsigned)__shfl_xor((int)vp, off, 64);
      vt += (unsigned)__shfl_xor((int)vt, off, 64);
    }
    if (lane == 0) {
      sprefix = vp;
      if (lt == 0) rp_all[rb + n] = vt;
    }
  }
  int i0 = base + t * 4;
  unsigned c[4] = {0u, 0u, 0u, 0u};
  #pragma unroll
  for (int j = 0; j < 4; ++j) {
    int i = i0 + j;
    if (i < n) {
      unsigned acc = 0;
      #pragma unroll
      for (int r = 0; r < NREP; ++r) {
        roff[r * CNT_LEN + cb + i] = acc;
        acc += cnt_rep[r * CNT_LEN + cb + i];
      }
      c[j] = acc;
    }
  }
  unsigned s4 = c[0] + c[1] + c[2] + c[3];
  unsigned inc = s4;
  #pragma unroll
  for (int off = 1; off < 64; off <<= 1) {
    unsigned v = (unsigned)__shfl_up((int)inc, off, 64);
    if (lane >= off) inc += v;
  }
  if (lane == 63) wt[wid] = inc;
  __syncthreads();
  unsigned wb = sprefix;
  #pragma unroll
  for (int w = 0; w < 4; ++w) if (w < wid) wb += wt[w];
  unsigned p0 = wb + inc - s4;
  unsigned p1 = p0 + c[0], p2 = p1 + c[1], p3 = p2 + c[2];
  if (i0 + 3 < n) {
    *(uint4*)&rp_all[rb + i0] = make_uint4(p0, p1, p2, p3);
  } else if (i0 < n) {
    rp_all[rb + i0] = p0;
    if (i0 + 1 < n) rp_all[rb + i0 + 1] = p1;
    if (i0 + 2 < n) rp_all[rb + i0 + 2] = p2;
  }
}

// ---------------- fill (rank+roff based, atomic-free, 4 edges/thread) + 4x d=6 proj ------
__global__ void fill_proj_kernel(const int* __restrict__ vv_s, const int* __restrict__ vv_d,
                                 const int* __restrict__ vi_s, const int* __restrict__ vi_d,
                                 const int* __restrict__ iv_s, const int* __restrict__ iv_d,
                                 const unsigned* __restrict__ rp_all,
                                 const unsigned* __restrict__ roff,
                                 const unsigned* __restrict__ rank_all,
                                 int* __restrict__ src_all,
                                 const float* __restrict__ x,
                                 const float* __restrict__ W0, const float* __restrict__ b0,
                                 const float* __restrict__ W1, const float* __restrict__ b1,
                                 const float* __restrict__ W2, const float* __restrict__ b2,
                                 const float* __restrict__ W3, const float* __restrict__ b3,
                                 __half* __restrict__ out0, __half* __restrict__ out1,
                                 __half* __restrict__ out2, __half* __restrict__ out3) {
  if (blockIdx.x < FB4) {
    int t0 = blockIdx.x * 1024 + threadIdx.x;
    #pragma unroll
    for (int j = 0; j < 4; ++j) {
      int e = t0 + j * 256;
      unsigned rb2 = (unsigned)((e >> 8) & (NREP - 1)) * CNT_LEN;
      if (e < EVV) {
        int s = vv_s[e], d = vv_d[e];
        if (s != d) {
          unsigned pos = rp_all[RB_VV + d] + roff[rb2 + CB_VV + d] + rank_all[e];
          __builtin_nontemporal_store(s, &src_all[pos]);
        }
      } else if (e < EVV + EVI) {
        int i = e - EVV;
        int d = vi_d[i];
        unsigned pos = rp_all[RB_VI + d] + roff[rb2 + CB_VI + d] + rank_all[e];
        __builtin_nontemporal_store(vi_s[i], &src_all[EVV + pos]);
      } else if (e < EVV + EVI + EIV) {
        int i = e - EVV - EVI;
        int d = iv_d[i];
        unsigned pos = rp_all[RB_IV + d] + roff[rb2 + CB_IV + d] + rank_all[e];
        __builtin_nontemporal_store(iv_s[i], &src_all[EVV + EVI + pos]);
      }
    }
  } else {
    int t = (blockIdx.x - FB4) * 256 + threadIdx.x;
    if (t >= NV * 64) return;
    int row = t >> 6, c = t & 63;
    const float* xr = x + (size_t)row * 6;
    float x0 = xr[0], x1 = xr[1], x2 = xr[2], x3 = xr[3], x4 = xr[4], x5 = xr[5];
    float a0 = b0[c], a1 = b1[c], a2 = b2[c], a3 = b3[c];
    a0 = fmaf(x0, W0[0 * 64 + c], a0); a1 = fmaf(x0, W1[0 * 64 + c], a1);
    a2 = fmaf(x0, W2[0 * 64 + c], a2); a3 = fmaf(x0, W3[0 * 64 + c], a3);
    a0 = fmaf(x1, W0[1 * 64 + c], a0); a1 = fmaf(x1, W1[1 * 64 + c], a1);
    a2 = fmaf(x1, W2[1 * 64 + c], a2); a3 = fmaf(x1, W3[1 * 64 + c], a3);
    a0 = fmaf(x2, W0[2 * 64 + c], a0); a1 = fmaf(x2, W1[2 * 64 + c], a1);
    a2 = fmaf(x2, W2[2 * 64 + c], a2); a3 = fmaf(x2, W3[2 * 64 + c], a3);
    a0 = fmaf(x3, W0[3 * 64 + c], a0); a1 = fmaf(x3, W1[3 * 64 + c], a1);
    a2 = fmaf(x3, W2[3 * 64 + c], a2); a3 = fmaf(x3, W3[3 * 64 + c], a3);
    a0 = fmaf(x4, W0[4 * 64 + c], a0); a1 = fmaf(x4, W1[4 * 64 + c], a1);
    a2 = fmaf(x4, W2[4 * 64 + c], a2); a3 = fmaf(x4, W3[4 * 64 + c], a3);
    a0 = fmaf(x5, W0[5 * 64 + c], a0); a1 = fmaf(x5, W1[5 * 64 + c], a1);
    a2 = fmaf(x5, W2[5 * 64 + c], a2); a3 = fmaf(x5, W3[5 * 64 + c], a3);
    out0[t] = __float2half(a0);
    out1[t] = __float2half(a1);
    out2[t] = __float2half(a2);
    out3[t] = __float2half(a3);
  }
}

// ---------------- quarter-wave GAT machinery ----------------
template <int R0>
__device__ __forceinline__ float redsum(float ee) {
  #pragma unroll
  for (int off = R0; off > 0; off >>= 1) ee += __shfl_xor(ee, off, 64);
  return ee;
}

__device__ __forceinline__ float4 cvt_h(int2 r) {
  __half2 ab = *(__half2*)&r.x;
  __half2 cd = *(__half2*)&r.y;
  float2 f0 = __half22float2(ab);
  float2 f1 = __half22float2(cd);
  return make_float4(f0.x, f0.y, f1.x, f1.y);
}
__device__ __forceinline__ float4 ldrow_h(const __half* p) { return cvt_h(*(const int2*)p); }

__device__ __forceinline__ void merge_groups(float& s, float4& a) {
  s   += __shfl_xor(s, 16, 64);
  a.x += __shfl_xor(a.x, 16, 64);
  a.y += __shfl_xor(a.y, 16, 64);
  a.z += __shfl_xor(a.z, 16, 64);
  a.w += __shfl_xor(a.w, 16, 64);
  s   += __shfl_xor(s, 32, 64);
  a.x += __shfl_xor(a.x, 32, 64);
  a.y += __shfl_xor(a.y, 32, 64);
  a.z += __shfl_xor(a.z, 32, 64);
  a.w += __shfl_xor(a.w, 32, 64);
}

template <int R0>
__device__ __forceinline__ void edge_acc(float4 p4, bool ok, float4 h, float4 a,
                                         float& s, float4& acc) {
  float vx = p4.x + h.x; vx = fmaxf(vx, 0.2f * vx);
  float vy = p4.y + h.y; vy = fmaxf(vy, 0.2f * vy);
  float vz = p4.z + h.z; vz = fmaxf(vz, 0.2f * vz);
  float vw = p4.w + h.w; vw = fmaxf(vw, 0.2f * vw);
  float ee = redsum<R0>(fmaf(vx, a.x, fmaf(vy, a.y, fmaf(vz, a.z, vw * a.w))));
  float w = ok ? __expf(ee) : 0.f;
  s += w;
  acc.x = fmaf(w, p4.x, acc.x);
  acc.y = fmaf(w, p4.y, acc.y);
  acc.z = fmaf(w, p4.z, acc.z);
  acc.w = fmaf(w, p4.w, acc.w);
}

template <int CHUNK, int NSLOT, int R0, bool MASK>
__device__ __forceinline__ void gat4_table(unsigned beg, unsigned end, unsigned slot,
                                           const int* __restrict__ srcs,
                                           const __half* __restrict__ tab, int q, int d,
                                           float4 h, float4 a, float& s, float4& acc) {
  for (unsigned i = beg + slot; i < end; i += NSLOT * CHUNK) {
    float4 p[CHUNK]; bool ok[CHUNK];
    #pragma unroll
    for (int j = 0; j < CHUNK; ++j) {
      unsigned idx = i + (unsigned)(j * NSLOT);
      int sv = (idx < end) ? srcs[idx] : 0;
      ok[j] = (idx < end) && (!MASK || sv != d);
      p[j] = ldrow_h(tab + (size_t)sv * 64 + 4 * q);
    }
    #pragma unroll
    for (int j = 0; j < CHUNK; ++j) edge_acc<R0>(p[j], ok[j], h, a, s, acc);
  }
}

// ---------------- layer 1 (heads=2; 2-stage pipeline; fp16 hr tables) ---------
__global__ __launch_bounds__(256)
void l1_all_kernel(const unsigned* __restrict__ rp_all, const int* __restrict__ src_all,
                   const __half* __restrict__ TA, const __half* __restrict__ TB,
                   const __half* __restrict__ HRVV, const __half* __restrict__ HRIV,
                   const float* __restrict__ x_rsu,
                   const float* __restrict__ Wl_iv, const float* __restrict__ bl_iv,
                   const float* __restrict__ att_vv, const float* __restrict__ att_iv,
                   const float* __restrict__ Wr_vi, const float* __restrict__ br_vi,
                   const float* __restrict__ att_vi,
                   const float* __restrict__ b_vv, const float* __restrict__ b_iv,
                   const float* __restrict__ b_vi,
                   float* __restrict__ ACCV, float* __restrict__ ACCR) {
  __shared__ float sS[4][64];
  __shared__ float4 sA[4][64];
  int tid = threadIdx.x, lane = tid & 63, wid = tid >> 6;
  int q = lane & 15, g = lane >> 4;
  if (blockIdx.x < GBV) {
    float4 av = *(const float4*)&att_vv[4 * q];
    float4 ai = *(const float4*)&att_iv[4 * q];
    float4 wli = *(const float4*)&Wl_iv[4 * q];
    float4 bli = *(const float4*)&bl_iv[4 * q];
    float4 bvv = *(const float4*)&b_vv[4 * q];
    float4 biv = *(const float4*)&b_iv[4 * q];
    float4 bb = make_float4(bvv.x + biv.x, bvv.y + biv.y, bvv.z + biv.z, bvv.w + biv.w);
    const int* src_iv = src_all + EVV + EVI;
    int d = blockIdx.x * 4 + wid;
    unsigned vb = 0, ve = 0, ib = 0, ie = 0;
    int psv0 = 0, psv1 = 0, pisv = 0;
    if (d < NV) {
      vb = rp_all[RB_VV + d]; ve = rp_all[RB_VV + d + 1];
      ib = rp_all[RB_IV + d]; ie = rp_all[RB_IV + d + 1];
      unsigned i0 = vb + (unsigned)g, i1 = i0 + 4;
      psv0 = (i0 < ve) ? src_all[i0] : 0;
      psv1 = (i1 < ve) ? src_all[i1] : 0;
      unsigned ii0 = ib + (unsigned)g;
      pisv = (ii0 < ie) ? src_iv[ii0] : 0;
    }
    while (d < NV) {
      int dn = d + GBV * 4;
      unsigned cvb = vb, cve = ve, cib = ib, cie = ie;
      int2 r0raw = *(const int2*)(TA + (size_t)psv0 * 64 + 4 * q);
      int2 r1raw = *(const int2*)(TA + (size_t)psv1 * 64 + 4 * q);
      float ixv = x_rsu[pisv];
      bool iok0 = (cib + (unsigned)g) < cie;
      if (dn < NV) {
        vb = rp_all[RB_VV + dn]; ve = rp_all[RB_VV + dn + 1];
        ib = rp_all[RB_IV + dn]; ie = rp_all[RB_IV + dn + 1];
      }
      float4 hv = ldrow_h(HRVV + (size_t)d * 64 + 4 * q);
      float4 hi = ldrow_h(HRIV + (size_t)d * 64 + 4 * q);
      float sv_ = 0.f; float4 av_ = make_float4(0.f, 0.f, 0.f, 0.f);
      edge_acc<4>(cvt_h(r0raw), (cvb + (unsigned)g) < cve, hv, av, sv_, av_);
      edge_acc<4>(cvt_h(r1raw), (cvb + (unsigned)g + 4) < cve, hv, av, sv_, av_);
      gat4_table<2, 4, 4, false>(cvb + 8, cve, (unsigned)g, src_all, TA, q, d, hv, av, sv_, av_);
      if (g == 0) {
        float4 p4 = ldrow_h(TA + (size_t)d * 64 + 4 * q);
        edge_acc<4>(p4, true, hv, av, sv_, av_);
      }
      merge_groups(sv_, av_);
      float si_ = 0.f; float4 ai_ = make_float4(0.f, 0.f, 0.f, 0.f);
      {
        float4 p4;
        p4.x = fmaf(ixv, wli.x, bli.x);
        p4.y = fmaf(ixv, wli.y, bli.y);
        p4.z = fmaf(ixv, wli.z, bli.z);
        p4.w = fmaf(ixv, wli.w, bli.w);
        edge_acc<4>(p4, iok0, hi, ai, si_, ai_);
      }
      for (unsigned i = cib + 4 + (unsigned)g; i < cie; i += 4) {
        int sv2 = src_iv[i];
        float xv2 = x_rsu[sv2];
        float4 p4;
        p4.x = fmaf(xv2, wli.x, bli.x);
        p4.y = fmaf(xv2, wli.y, bli.y);
        p4.z = fmaf(xv2, wli.z, bli.z);
        p4.w = fmaf(xv2, wli.w, bli.w);
        edge_acc<4>(p4, true, hi, ai, si_, ai_);
      }
      merge_groups(si_, ai_);
      if (dn < NV) {
        unsigned i0 = vb + (unsigned)g, i1 = i0 + 4;
        psv0 = (i0 < ve) ? src_all[i0] : 0;
        psv1 = (i1 < ve) ? src_all[i1] : 0;
        unsigned ii0 = ib + (unsigned)g;
        pisv = (ii0 < ie) ? src_iv[ii0] : 0;
      }
      if (g == 0) {
        float rv = 1.f / (sv_ + 1e-16f), ri = 1.f / (si_ + 1e-16f);
        float v0 = av_.x * rv + ai_.x * ri + bb.x;
        float v1 = av_.y * rv + ai_.y * ri + bb.y;
        float v2 = av_.z * rv + ai_.z * ri + bb.z;
        float v3 = av_.w * rv + ai_.w * ri + bb.w;
        float4 o;
        o.x = (v0 > 0.f) ? v0 : expm1f(v0);
        o.y = (v1 > 0.f) ? v1 : expm1f(v1);
        o.z = (v2 > 0.f) ? v2 : expm1f(v2);
        o.w = (v3 > 0.f) ? v3 : expm1f(v3);
        *(float4*)&ACCV[(size_t)d * 64 + 4 * q] = o;
      }
      d = dn;
    }
  } else {
    int d = (int)blockIdx.x - GBV;
    float xv = x_rsu[d];
    float4 wrv = *(const float4*)&Wr_vi[4 * q];
    float4 brv = *(const float4*)&br_vi[4 * q];
    float4 h;
    h.x = fmaf(xv, wrv.x, brv.x);
    h.y = fmaf(xv, wrv.y, brv.y);
    h.z = fmaf(xv, wrv.z, brv.z);
    h.w = fmaf(xv, wrv.w, brv.w);
    float4 a = *(const float4*)&att_vi[4 * q];
    float s_ = 0.f; float4 a_ = make_float4(0.f, 0.f, 0.f, 0.f);
    gat4_table<4, 16, 4, false>(rp_all[RB_VI + d], rp_all[RB_VI + d + 1],
                                (unsigned)(wid * 4 + g), src_all + EVV, TB, q, d,
                                h, a, s_, a_);
    merge_groups(s_, a_);
    if (wid != 0) { sS[wid][lane] = s_; sA[wid][lane] = a_; }
    __syncthreads();
    if (wid == 0) {
      #pragma unroll
      for (int w2 = 1; w2 < 4; ++w2) {
        s_ += sS[w2][lane];
        float4 t = sA[w2][lane];
        a_.x += t.x; a_.y += t.y; a_.z += t.z; a_.w += t.w;
      }
      if (g == 0) {
        float4 bvi = *(const float4*)&b_vi[4 * q];
        float inv = 1.f / (s_ + 1e-16f);
        float v0 = a_.x * inv + bvi.x;
        float v1 = a_.y * inv + bvi.y;
        float v2 = a_.z * inv + bvi.z;
        float v3 = a_.w * inv + bvi.w;
        float4 o;
        o.x = (v0 > 0.f) ? v0 : expm1f(v0);
        o.y = (v1 > 0.f) ? v1 : expm1f(v1);
        o.z = (v2 > 0.f) ? v2 : expm1f(v2);
        o.w = (v3 > 0.f) ? v3 : expm1f(v3);
        *(float4*)&ACCR[(size_t)d * 64 + 4 * q] = o;
      }
    }
  }
}

// ---------------- layer-2 projections: quad (veh) + dual (rsu); fp16 hl AND hr ----------
__global__ __launch_bounds__(256, 2)
void quad_proj_kernel(const float* __restrict__ ACCVin, const float* __restrict__ ACCR,
                      const float* __restrict__ W0, const float* __restrict__ b0,
                      const float* __restrict__ W1, const float* __restrict__ b1,
                      const float* __restrict__ W2, const float* __restrict__ b2,
                      const float* __restrict__ W3, const float* __restrict__ b3,
                      const float* __restrict__ W4, const float* __restrict__ b4,
                      const float* __restrict__ W5, const float* __restrict__ b5,
                      __half* __restrict__ O0, __half* __restrict__ O1,
                      __half* __restrict__ O2, __half* __restrict__ O3,
                      __half* __restrict__ S0o, float* __restrict__ S1o) {
  __shared__ float w0s[4096], w1s[4096], w2s[4096], w3s[4096], xtile[2048];
  int t = threadIdx.x;
  bool vehb = blockIdx.x < NBQ;
  const float* X = vehb ? ACCVin : ACCR;
  int n = vehb ? NV : NR;
  int base = (vehb ? (int)blockIdx.x : (int)blockIdx.x - NBQ) * 32;
  if (vehb) {
    for (int i = t; i < 4096; i += 256) { w0s[i] = W0[i]; w1s[i] = W1[i]; w2s[i] = W2[i]; w3s[i] = W3[i]; }
  } else {
    for (int i = t; i < 4096; i += 256) { w0s[i] = W4[i]; w1s[i] = W5[i]; }
  }
  for (int i = t; i < 2048; i += 256) {
    int row = base + (i >> 6);
    int rc = (row < n) ? row : (n - 1);
    xtile[i] = X[(size_t)rc * 64 + (i & 63)];
  }
  __syncthreads();
  int lane = t & 63, wid = t >> 6;
  int wr = wid * 8;
  int p = 4 * (lane & 15) + (lane >> 4);
  if (vehb) {
    float a0[8], a1[8], a2[8], a3[8];
    #pragma unroll
    for (int r = 0; r < 8; ++r) { a0[r] = 0.f; a1[r] = 0.f; a2[r] = 0.f; a3[r] = 0.f; }
    for (int kq = 0; kq < 16; ++kq) {
      int k = kq * 4;
      float u00 = w0s[(k + 0) * 64 + lane], u01 = w0s[(k + 1) * 64 + lane];
      float u02 = w0s[(k + 2) * 64 + lane], u03 = w0s[(k + 3) * 64 + lane];
      float u10 = w1s[(k + 0) * 64 + lane], u11 = w1s[(k + 1) * 64 + lane];
      float u12 = w1s[(k + 2) * 64 + lane], u13 = w1s[(k + 3) * 64 + lane];
      float u20 = w2s[(k + 0) * 64 + lane], u21 = w2s[(k + 1) * 64 + lane];
      float u22 = w2s[(k + 2) * 64 + lane], u23 = w2s[(k + 3) * 64 + lane];
      float u30 = w3s[(k + 0) * 64 + lane], u31 = w3s[(k + 1) * 64 + lane];
      float u32 = w3s[(k + 2) * 64 + lane], u33 = w3s[(k + 3) * 64 + lane];
      #pragma unroll
      for (int r = 0; r < 8; ++r) {
        float4 xv = *(const float4*)&xtile[(wr + r) * 64 + k];
        a0[r] = fmaf(xv.x, u00, a0[r]); a0[r] = fmaf(xv.y, u01, a0[r]);
        a0[r] = fmaf(xv.z, u02, a0[r]); a0[r] = fmaf(xv.w, u03, a0[r]);
        a1[r] = fmaf(xv.x, u10, a1[r]); a1[r] = fmaf(xv.y, u11, a1[r]);
        a1[r] = fmaf(xv.z, u12, a1[r]); a1[r] = fmaf(xv.w, u13, a1[r]);
        a2[r] = fmaf(xv.x, u20, a2[r]); a2[r] = fmaf(xv.y, u21, a2[r]);
        a2[r] = fmaf(xv.z, u22, a2[r]); a2[r] = fmaf(xv.w, u23, a2[r]);
        a3[r] = fmaf(xv.x, u30, a3[r]); a3[r] = fmaf(xv.y, u31, a3[r]);
        a3[r] = fmaf(xv.z, u32, a3[r]); a3[r] = fmaf(xv.w, u33, a3[r]);
      }
    }
    float c0 = b0[lane], c1 = b1[lane], c2 = b2[lane], c3 = b3[lane];
    #pragma unroll
    for (int r = 0; r < 8; ++r) {
      int row = base + wr + r;
      if (row < n) {
        O0[(size_t)row * 64 + p] = __float2half(a0[r] + c0);
        O1[(size_t)row * 64 + p] = __float2half(a1[r] + c1);
        O2[(size_t)row * 64 + p] = __float2half(a2[r] + c2);
        O3[(size_t)row * 64 + p] = __float2half(a3[r] + c3);
      }
    }
  } else {
    float a0[8], a1[8];
    #pragma unroll
    for (int r = 0; r < 8; ++r) { a0[r] = 0.f; a1[r] = 0.f; }
    for (int kq = 0; kq < 16; ++kq) {
      int k = kq * 4;
      float u00 = w0s[(k + 0) * 64 + lane], u01 = w0s[(k + 1) * 64 + lane];
      float u02 = w0s[(k + 2) * 64 + lane], u03 = w0s[(k + 3) * 64 + lane];
      float u10 = w1s[(k + 0) * 64 + lane], u11 = w1s[(k + 1) * 64 + lane];
      float u12 = w1s[(k + 2) * 64 + lane], u13 = w1s[(k + 3) * 64 + lane];
      #pragma unroll
      for (int r = 0; r < 8; ++r) {
        float4 xv = *(const float4*)&xtile[(wr + r) * 64 + k];
        a0[r] = fmaf(xv.x, u00, a0[r]); a0[r] = fmaf(xv.y, u01, a0[r]);
        a0[r] = fmaf(xv.z, u02, a0[r]); a0[r] = fmaf(xv.w, u03, a0[r]);
        a1[r] = fmaf(xv.x, u10, a1[r]); a1[r] = fmaf(xv.y, u11, a1[r]);
        a1[r] = fmaf(xv.z, u12, a1[r]); a1[r] = fmaf(xv.w, u13, a1[r]);
      }
    }
    float c0 = b4[lane], c1 = b5[lane];
    #pragma unroll
    for (int r = 0; r < 8; ++r) {
      int row = base + wr + r;
      if (row < n) {
        S0o[(size_t)row * 64 + p] = __float2half(a0[r] + c0);
        S1o[(size_t)row * 64 + p] = a1[r] + c1;
      }
    }
  }
}

// ---------------- layer 2 (heads=1; 2-stage pipeline; fp16 hl AND hr) --------------------
__global__ __launch_bounds__(256)
void l2_all_kernel(const unsigned* __restrict__ rp_all, const int* __restrict__ src_all,
                   const __half* __restrict__ Tvvl, const __half* __restrict__ Tvvr,
                   const __half* __restrict__ Tivl, const __half* __restrict__ Tivr,
                   const __half* __restrict__ Tvil, const float* __restrict__ Tvir,
                   const float* __restrict__ att_vv, const float* __restrict__ att_iv,
                   const float* __restrict__ att_vi,
                   const float* __restrict__ b_vv, const float* __restrict__ b_iv,
                   const float* __restrict__ b_vi,
                   const float* __restrict__ lnv_w, const float* __restrict__ lnv_b,
                   const float* __restrict__ lnr_w, const float* __restrict__ lnr_b,
                   float* __restrict__ outv, float* __restrict__ outr) {
  __shared__ float sS[4][64];
  __shared__ float4 sA[4][64];
  int tid = threadIdx.x, lane = tid & 63, wid = tid >> 6;
  int q = lane & 15, g = lane >> 4;
  if (blockIdx.x < GBV) {
    float4 av = make_float4(att_vv[q], att_vv[q + 16], att_vv[q + 32], att_vv[q + 48]);
    float4 ai = make_float4(att_iv[q], att_iv[q + 16], att_iv[q + 32], att_iv[q + 48]);
    float4 bb = make_float4(b_vv[q] + b_iv[q], b_vv[q + 16] + b_iv[q + 16],
                            b_vv[q + 32] + b_iv[q + 32], b_vv[q + 48] + b_iv[q + 48]);
    float4 lw = make_float4(lnv_w[q], lnv_w[q + 16], lnv_w[q + 32], lnv_w[q + 48]);
    float4 lb = make_float4(lnv_b[q], lnv_b[q + 16], lnv_b[q + 32], lnv_b[q + 48]);
    const int* src_iv = src_all + EVV + EVI;
    int d = blockIdx.x * 4 + wid;
    unsigned vb = 0, ve = 0, ib = 0, ie = 0;
    int psv0 = 0, psv1 = 0, pisv = 0;
    if (d < NV) {
      vb = rp_all[RB_VV + d]; ve = rp_all[RB_VV + d + 1];
      ib = rp_all[RB_IV + d]; ie = rp_all[RB_IV + d + 1];
      unsigned i0 = vb + (unsigned)g, i1 = i0 + 4;
      psv0 = (i0 < ve) ? src_all[i0] : 0;
      psv1 = (i1 < ve) ? src_all[i1] : 0;
      unsigned ii0 = ib + (unsigned)g;
      pisv = (ii0 < ie) ? src_iv[ii0] : 0;
    }
    while (d < NV) {
      int dn = d + GBV * 4;
      unsigned cvb = vb, cve = ve, cib = ib, cie = ie;
      int cisv = pisv;
      int2 r0raw = *(const int2*)(Tvvl + (size_t)psv0 * 64 + 4 * q);
      int2 r1raw = *(const int2*)(Tvvl + (size_t)psv1 * 64 + 4 * q);
      int2 ipraw = *(const int2*)(Tivl + (size_t)cisv * 64 + 4 * q);
      bool iok0 = (cib + (unsigned)g) < cie;
      if (dn < NV) {
        vb = rp_all[RB_VV + dn]; ve = rp_all[RB_VV + dn + 1];
        ib = rp_all[RB_IV + dn]; ie = rp_all[RB_IV + dn + 1];
      }
      float4 hv = ldrow_h(Tvvr + (size_t)d * 64 + 4 * q);
      float4 hi = ldrow_h(Tivr + (size_t)d * 64 + 4 * q);
      float sv_ = 0.f; float4 av_ = make_float4(0.f, 0.f, 0.f, 0.f);
      edge_acc<8>(cvt_h(r0raw), (cvb + (unsigned)g) < cve, hv, av, sv_, av_);
      edge_acc<8>(cvt_h(r1raw), (cvb + (unsigned)g + 4) < cve, hv, av, sv_, av_);
      gat4_table<2, 4, 8, false>(cvb + 8, cve, (unsigned)g, src_all, Tvvl, q, d, hv, av, sv_, av_);
      if (g == 0) {
        float4 p4 = ldrow_h(Tvvl + (size_t)d * 64 + 4 * q);
        edge_acc<8>(p4, true, hv, av, sv_, av_);
      }
      merge_groups(sv_, av_);
      float si_ = 0.f; float4 ai_ = make_float4(0.f, 0.f, 0.f, 0.f);
      edge_acc<8>(cvt_h(ipraw), iok0 && (cisv != d), hi, ai, si_, ai_);
      for (unsigned i = cib + 4 + (unsigned)g; i < cie; i += 4) {
        int sv2 = src_iv[i];
        float4 p4 = ldrow_h(Tivl + (size_t)sv2 * 64 + 4 * q);
        edge_acc<8>(p4, sv2 != d, hi, ai, si_, ai_);
      }
      if (g == 0 && d < NR) {
        float4 p4 = ldrow_h(Tivl + (size_t)d * 64 + 4 * q);
        edge_acc<8>(p4, true, hi, ai, si_, ai_);
      }
      merge_groups(si_, ai_);
      if (dn < NV) {
        unsigned i0 = vb + (unsigned)g, i1 = i0 + 4;
        psv0 = (i0 < ve) ? src_all[i0] : 0;
        psv1 = (i1 < ve) ? src_all[i1] : 0;
        unsigned ii0 = ib + (unsigned)g;
        pisv = (ii0 < ie) ? src_iv[ii0] : 0;
      }
      float rv = 1.f / (sv_ + 1e-16f), ri = 1.f / (si_ + 1e-16f);
      float v0 = av_.x * rv + ai_.x * ri + bb.x;
      float v1 = av_.y * rv + ai_.y * ri + bb.y;
      float v2 = av_.z * rv + ai_.z * ri + bb.z;
      float v3 = av_.w * rv + ai_.w * ri + bb.w;
      float sum = redsum<8>(v0 + v1 + v2 + v3);
      float mu = sum * (1.f / 64.f);
      float d0 = v0 - mu, d1 = v1 - mu, d2 = v2 - mu, d3 = v3 - mu;
      float qq = redsum<8>(d0 * d0 + d1 * d1 + d2 * d2 + d3 * d3);
      float is = rsqrtf(qq * (1.f / 64.f) + 1e-5f);
      if (g == 0) {
        outv[(size_t)d * 64 + q]      = d0 * is * lw.x + lb.x;
        outv[(size_t)d * 64 + q + 16] = d1 * is * lw.y + lb.y;
        outv[(size_t)d * 64 + q + 32] = d2 * is * lw.z + lb.z;
        outv[(size_t)d * 64 + q + 48] = d3 * is * lw.w + lb.w;
      }
      d = dn;
    }
  } else {
    int d = (int)blockIdx.x - GBV;
    float4 h = *(const float4*)&Tvir[(size_t)d * 64 + 4 * q];
    float4 a = make_float4(att_vi[q], att_vi[q + 16], att_vi[q + 32], att_vi[q + 48]);
    float s_ = 0.f; float4 a_ = make_float4(0.f, 0.f, 0.f, 0.f);
    gat4_table<4, 16, 8, true>(rp_all[RB_VI + d], rp_all[RB_VI + d + 1],
                               (unsigned)(wid * 4 + g), src_all + EVV, Tvil, q, d,
                               h, a, s_, a_);
    if (wid == 0 && g == 0) {
      float4 p4 = ldrow_h(Tvil + (size_t)d * 64 + 4 * q);
      edge_acc<8>(p4, true, h, a, s_, a_);
    }
    merge_groups(s_, a_);
    if (wid != 0) { sS[wid][lane] = s_; sA[wid][lane] = a_; }
    __syncthreads();
    if (wid == 0) {
      #pragma unroll
      for (int w2 = 1; w2 < 4; ++w2) {
        s_ += sS[w2][lane];
        float4 t = sA[w2][lane];
        a_.x += t.x; a_.y += t.y; a_.z += t.z; a_.w += t.w;
      }
      float inv = 1.f / (s_ + 1e-16f);
      float v0 = a_.x * inv + b_vi[q];
      float v1 = a_.y * inv + b_vi[q + 16];
      float v2 = a_.z * inv + b_vi[q + 32];
      float v3 = a_.w * inv + b_vi[q + 48];
      float sum = redsum<8>(v0 + v1 + v2 + v3);
      float mu = sum * (1.f / 64.f);
      float d0 = v0 - mu, d1 = v1 - mu, d2 = v2 - mu, d3 = v3 - mu;
      float qq = redsum<8>(d0 * d0 + d1 * d1 + d2 * d2 + d3 * d3);
      float is = rsqrtf(qq * (1.f / 64.f) + 1e-5f);
      if (g == 0) {
        outr[(size_t)d * 64 + q]      = d0 * is * lnr_w[q] + lnr_b[q];
        outr[(size_t)d * 64 + q + 16] = d1 * is * lnr_w[q + 16] + lnr_b[q + 16];
        outr[(size_t)d * 64 + q + 32] = d2 * is * lnr_w[q + 32] + lnr_b[q + 32];
        outr[(size_t)d * 64 + q + 48] = d3 * is * lnr_w[q + 48] + lnr_b[q + 48];
      }
    }
  }
}

extern "C" void kernel_launch(void* const* d_in, const int* in_sizes, int n_in,
                              void* d_out, int out_size, void* d_ws, size_t ws_size,
                              hipStream_t stream) {
  const float* x_veh = (const float*)d_in[0];
  const float* x_rsu = (const float*)d_in[1];
  const int* ei_v2v = (const int*)d_in[2];
  const int* ei_v2i = (const int*)d_in[3];
  const int* ei_i2v = (const int*)d_in[4];
  const float* P[36];
  for (int i = 0; i < 36; ++i) P[i] = (const float*)d_in[5 + i];
  const float* lnv_w = (const float*)d_in[41];
  const float* lnv_b = (const float*)d_in[42];
  const float* lnr_w = (const float*)d_in[43];
  const float* lnr_b = (const float*)d_in[44];

  float* ws = (float*)d_ws;
  float* P0    = ws;
  float* P1    = P0 + 3200000;
  float* ACCV  = P1 + 3200000;
  float* ACC2V = ACCV + 3200000;
  float* S0    = ACC2V + 3200000;
  float* S1    = S0 + 32000;
  float* ACCR  = S1 + 32000;
  unsigned* rp_all     = (unsigned*)(ACCR + 32000);
  unsigned* tsum       = rp_all + RP_LEN;
  unsigned* rank_all   = tsum + 128;
  int* src_all         = (int*)(rank_all + 600000);
  unsigned* cnt_rep    = (unsigned*)ACCV;
  unsigned* roff       = cnt_rep + NREP * CNT_LEN;
  __half* TA_h   = (__half*)ACC2V;
  __half* TB_h   = (__half*)(ACC2V + 1600000);
  __half* HRVV_h = (__half*)P1;
  __half* HRIV_h = (__half*)P0;
  __half* Tvvl_h = (__half*)P0;
  __half* Tvil_h = (__half*)(P0 + 1600000);
  __half* Tvvr_h = (__half*)P1;
  __half* Tivr_h = (__half*)ACC2V;
  __half* Tivl_h = (__half*)S0;

  // ---- CSR build (XCD-local replicated counters) + layer-1 tables ----
  hipMemsetAsync(cnt_rep, 0, (size_t)NREP * CNT_LEN * 4, stream);
  hist_all_kernel<<<HB1, 256, 0, stream>>>(
      ei_v2v, ei_v2v + EVV, ei_v2i + EVI, ei_i2v + EIV, cnt_rep, rank_all);
  tilesum_kernel<<<T_TOT, 256, 0, stream>>>(cnt_rep, tsum);
  scanwrite_kernel<<<T_TOT, 256, 0, stream>>>(cnt_rep, tsum, rp_all, roff);
  fill_proj_kernel<<<FB4 + PB, 256, 0, stream>>>(
      ei_v2v, ei_v2v + EVV, ei_v2i, ei_v2i + EVI, ei_i2v, ei_i2v + EIV,
      rp_all, roff, rank_all, src_all,
      x_veh, P[0], P[1], P[6], P[7], P[2], P[3], P[14], P[15],
      TA_h, TB_h, HRVV_h, HRIV_h);

  // ---- layer 1 ----
  l1_all_kernel<<<GBV + NR, 256, 0, stream>>>(
      rp_all, src_all, TA_h, TB_h, HRVV_h, HRIV_h, x_rsu,
      P[12], P[13],
      P[4], P[16],
      P[8], P[9], P[10],
      P[5], P[17], P[11],
      ACCV, ACCR);

  // ---- layer-2 projections ----
  quad_proj_kernel<<<NBQ + RSB, 256, 0, stream>>>(
      ACCV, ACCR,
      P[18], P[19],
      P[20], P[21],
      P[32], P[33],
      P[24], P[25],
      P[30], P[31],
      P[26], P[27],
      Tvvl_h, Tvvr_h, Tivr_h, Tvil_h, Tivl_h, S1);

  // ---- layer 2 ----
  l2_all_kernel<<<GBV + NR, 256, 0, stream>>>(
      rp_all, src_all,
      Tvvl_h, Tvvr_h, Tivl_h, Tivr_h, Tvil_h, S1,
      P[22], P[34], P[28],
      P[23], P[35], P[29],
      lnv_w, lnv_b, lnr_w, lnr_b,
      (float*)d_out, (float*)d_out + (size_t)NV * 64);
}